// Round 1
// baseline (88.940 us; speedup 1.0000x reference)
//
#include <hip/hip_runtime.h>
#include <math.h>

#define D 100
#define K 4
#define NTHREADS 256

__global__ __launch_bounds__(NTHREADS) void ntn_kernel(
    const int* __restrict__ heads,
    const int* __restrict__ tails,
    const int* __restrict__ rels,
    const float* __restrict__ E,
    const float* __restrict__ W,
    const float* __restrict__ V,
    const float* __restrict__ Bp,
    const float* __restrict__ U,
    float* __restrict__ out,
    int B)
{
    const int b = blockIdx.x;
    if (b >= B) return;
    const int tid = threadIdx.x;

    const int h = heads[b];
    const int t = tails[b];
    const int r = rels[b];

    __shared__ float e12[2 * D];   // [e1 ; e2]
    for (int i = tid; i < 2 * D; i += NTHREADS) {
        e12[i] = (i < D) ? E[(long)h * D + i] : E[(long)t * D + (i - D)];
    }
    __syncthreads();

    const float* e1s = e12;
    const float* e2s = e12 + D;

    // W[r] : K x D x D floats; use float4 loads (D*D/4 = 2500 float4 per slice,
    // 25 float4 per row, so a float4 never straddles a row boundary).
    const float4* W4 = reinterpret_cast<const float4*>(W + (long)r * K * D * D);
    const float*  Vr = V + (long)r * K * 2 * D;

    float partial[K];
    #pragma unroll
    for (int k = 0; k < K; ++k) {
        float acc = 0.f;
        const float4* Wk = W4 + k * (D * D / 4);
        for (int i4 = tid; i4 < D * D / 4; i4 += NTHREADS) {
            float4 w = Wk[i4];
            int d  = i4 / 25;        // row index
            int e0 = (i4 % 25) * 4;  // col base
            float dot = w.x * e2s[e0]     + w.y * e2s[e0 + 1]
                      + w.z * e2s[e0 + 2] + w.w * e2s[e0 + 3];
            acc += dot * e1s[d];
        }
        // g_a contribution: v[r,k,:] . [e1;e2]  (200 terms, one per thread)
        if (tid < 2 * D) acc += Vr[k * 2 * D + tid] * e12[tid];
        partial[k] = acc;
    }

    // Block reduction: wave64 shuffle, then cross-wave via LDS.
    __shared__ float red[NTHREADS / 64][K];
    const int lane = tid & 63;
    const int wid  = tid >> 6;
    #pragma unroll
    for (int k = 0; k < K; ++k) {
        float v = partial[k];
        #pragma unroll
        for (int off = 32; off > 0; off >>= 1)
            v += __shfl_down(v, off, 64);
        if (lane == 0) red[wid][k] = v;
    }
    __syncthreads();

    if (tid == 0) {
        float score = 0.f;
        #pragma unroll
        for (int k = 0; k < K; ++k) {
            float g = red[0][k] + red[1][k] + red[2][k] + red[3][k];
            g += Bp[r * K + k];
            score += U[r * K + k] * tanhf(g);
        }
        out[b] = 1.f / (1.f + expf(-score));
    }
}

extern "C" void kernel_launch(void* const* d_in, const int* in_sizes, int n_in,
                              void* d_out, int out_size, void* d_ws, size_t ws_size,
                              hipStream_t stream) {
    const int*   heads = (const int*)d_in[0];
    const int*   tails = (const int*)d_in[1];
    const int*   rels  = (const int*)d_in[2];
    const float* E     = (const float*)d_in[3];
    const float* W     = (const float*)d_in[4];
    const float* V     = (const float*)d_in[5];
    const float* Bp    = (const float*)d_in[6];
    const float* U     = (const float*)d_in[7];
    float* out = (float*)d_out;

    const int B = in_sizes[0];
    ntn_kernel<<<B, NTHREADS, 0, stream>>>(heads, tails, rels, E, W, V, Bp, U, out, B);
}

// Round 2
// 56.204 us; speedup vs baseline: 1.5825x; 1.5825x over previous
//
#include <hip/hip_runtime.h>
#include <math.h>

#define D 100
#define K 4
#define NREL 1000
#define CH 8
#define NT 256

// --- Setup: group batch indices by relation (histogram + scan + scatter) ---
__global__ __launch_bounds__(1024) void group_kernel(const int* __restrict__ rels, int B,
                                                     int* __restrict__ start,
                                                     int* __restrict__ bucket) {
    __shared__ int cnt[NREL];
    __shared__ int sA[1024], sB[1024];
    const int tid = threadIdx.x;
    for (int i = tid; i < NREL; i += 1024) cnt[i] = 0;
    __syncthreads();
    for (int b = tid; b < B; b += 1024) atomicAdd(&cnt[rels[b]], 1);
    __syncthreads();
    const int v = (tid < NREL) ? cnt[tid] : 0;
    sA[tid] = v;
    __syncthreads();
    int* src = sA; int* dst = sB;
    for (int off = 1; off < 1024; off <<= 1) {
        int x = src[tid];
        if (tid >= off) x += src[tid - off];
        dst[tid] = x;
        __syncthreads();
        int* t = src; src = dst; dst = t;
    }
    const int excl = src[tid] - v;   // exclusive scan
    __syncthreads();
    if (tid < NREL) {
        start[tid] = excl;
        cnt[tid] = excl;             // reuse as cursor
    }
    if (tid == 0) start[NREL] = B;
    __syncthreads();
    for (int b = tid; b < B; b += 1024) {
        int r = rels[b];
        int pos = atomicAdd(&cnt[r], 1);
        bucket[pos] = b;
    }
}

// --- Main: one block per relation; W[r] read once, applied to all its items ---
__global__ __launch_bounds__(NT) void ntn_main(
    const int* __restrict__ heads, const int* __restrict__ tails,
    const float* __restrict__ E, const float* __restrict__ W,
    const float* __restrict__ V, const float* __restrict__ Bp,
    const float* __restrict__ U, const int* __restrict__ start,
    const int* __restrict__ bucket, float* __restrict__ out)
{
    const int r = blockIdx.x;
    const int cs = start[r];
    const int n = start[r + 1] - cs;
    if (n <= 0) return;

    const int tid  = threadIdx.x;
    const int lane = tid & 63;
    const int k    = tid >> 6;            // wave id == tensor slice
    const int dsub = lane / 25;           // 0/1 valid, lanes >= 50 idle in bilinear loop
    const int c    = lane % 25;           // float4 column group within a row
    const bool active = (lane < 50);

    __shared__ float e12[CH][2 * D];
    __shared__ float red[K][CH];
    __shared__ int   bb[CH];

    const float* Wr = W + (size_t)r * K * D * D;
    const float* Vr = V + (size_t)r * K * 2 * D;

    for (int base = 0; base < n; base += CH) {
        const int m = min(CH, n - base);
        if (tid < CH) bb[tid] = (tid < m) ? bucket[cs + base + tid] : -1;
        __syncthreads();
        for (int idx = tid; idx < CH * 2 * D; idx += NT) {
            const int it = idx / (2 * D), j = idx % (2 * D);
            float val = 0.f;
            const int b = bb[it];
            if (b >= 0) {
                const int ent = (j < D) ? heads[b] : tails[b];
                val = E[(size_t)ent * D + (j < D ? j : j - D)];
            }
            e12[it][j] = val;
        }
        __syncthreads();

        // e2 column-group for every item -> registers (read once per chunk)
        float4 e2reg[CH];
        #pragma unroll
        for (int it = 0; it < CH; ++it)
            e2reg[it] = active ? *(const float4*)&e12[it][D + c * 4]
                               : make_float4(0.f, 0.f, 0.f, 0.f);

        float acc[CH];
        #pragma unroll
        for (int it = 0; it < CH; ++it) acc[it] = 0.f;

        const float* Wk = Wr + k * D * D;
        if (active) {
            #pragma unroll 2
            for (int dpair = 0; dpair < D / 2; ++dpair) {
                const int d = dpair * 2 + dsub;
                const float4 w = *(const float4*)&Wk[d * D + c * 4];
                const float e1d = e12[0][d]; // dummy to keep LDS read near use? (no)
                (void)e1d;
                #pragma unroll
                for (int it = 0; it < CH; ++it) {
                    float dot = w.x * e2reg[it].x + w.y * e2reg[it].y
                              + w.z * e2reg[it].z + w.w * e2reg[it].w;
                    acc[it] += dot * e12[it][d];
                }
            }
        }
        // g_a: v[r,k,:] . [e1;e2]
        for (int j = lane; j < 2 * D; j += 64) {
            const float vv = Vr[k * 2 * D + j];
            #pragma unroll
            for (int it = 0; it < CH; ++it) acc[it] += vv * e12[it][j];
        }
        // wave reduction per item
        #pragma unroll
        for (int it = 0; it < CH; ++it) {
            float s = acc[it];
            #pragma unroll
            for (int off = 32; off > 0; off >>= 1) s += __shfl_down(s, off, 64);
            if (lane == 0) red[k][it] = s;
        }
        __syncthreads();
        if (tid < m) {
            float score = 0.f;
            #pragma unroll
            for (int kk = 0; kk < K; ++kk) {
                const float g = red[kk][tid] + Bp[r * K + kk];
                score += U[r * K + kk] * tanhf(g);
            }
            out[bb[tid]] = 1.f / (1.f + expf(-score));
        }
        __syncthreads();
    }
}

extern "C" void kernel_launch(void* const* d_in, const int* in_sizes, int n_in,
                              void* d_out, int out_size, void* d_ws, size_t ws_size,
                              hipStream_t stream) {
    const int*   heads = (const int*)d_in[0];
    const int*   tails = (const int*)d_in[1];
    const int*   rels  = (const int*)d_in[2];
    const float* E     = (const float*)d_in[3];
    const float* W     = (const float*)d_in[4];
    const float* V     = (const float*)d_in[5];
    const float* Bp    = (const float*)d_in[6];
    const float* U     = (const float*)d_in[7];
    float* out = (float*)d_out;

    const int B = in_sizes[0];
    int* start  = (int*)d_ws;          // [NREL+1]
    int* bucket = start + 1024;        // [B]

    group_kernel<<<1, 1024, 0, stream>>>(rels, B, start, bucket);
    ntn_main<<<NREL, NT, 0, stream>>>(heads, tails, E, W, V, Bp, U, start, bucket, out);
}